// Round 3
// baseline (153.515 us; speedup 1.0000x reference)
//
#include <hip/hip_runtime.h>
#include <hip/hip_bf16.h>
#include <math.h>

// FM model: out[s] = sigmoid(0.5*sum_e((sum_f v[s,f,e])^2 - sum_f v[s,f,e]^2)
//                           + sum_f linear[s,f])
// feats = concat(user[16384,20,33], ctx[16384,10,33], doc[16384,30,33], axis=1)
// v = feats[...,:32], linear = feats[...,32]
//
// Strategy: 32 lanes per sample, lane l owns latent element l.
// Each row read = 32 lanes x 4B = 128B contiguous (coalesced); rows are
// contiguous so the whole per-sample blob streams densely. Linear elements
// (col 32) are issued first so they're in flight before the row stream and
// hit the same cache lines.

#define NS 16384
#define NU 20
#define NC 10
#define ND 30
#define RW 33  // row width in floats

__global__ __launch_bounds__(256) void fm_kernel(
    const float* __restrict__ user,
    const float* __restrict__ ctx,
    const float* __restrict__ doc,
    float* __restrict__ out) {
  const int tid   = blockIdx.x * blockDim.x + threadIdx.x;
  const int samp  = tid >> 5;   // 32-lane group per sample
  const int lane  = tid & 31;

  const float* __restrict__ ub = user + (size_t)samp * (NU * RW);
  const float* __restrict__ cb = ctx  + (size_t)samp * (NC * RW);
  const float* __restrict__ db = doc  + (size_t)samp * (ND * RW);

  // linear terms first: lane f reads row f's last element (col 32).
  // Issued early so these (stride-132B) requests overlap the row stream.
  float lin = 0.f;
  if (lane < NU) lin += ub[lane * RW + 32];
  if (lane < NC) lin += cb[lane * RW + 32];
  if (lane < ND) lin += db[lane * RW + 32];

  float sv = 0.f, sv2 = 0.f;

#pragma unroll
  for (int f = 0; f < NU; ++f) {
    float x = ub[f * RW + lane];
    sv += x; sv2 = fmaf(x, x, sv2);
  }
#pragma unroll
  for (int f = 0; f < NC; ++f) {
    float x = cb[f * RW + lane];
    sv += x; sv2 = fmaf(x, x, sv2);
  }
#pragma unroll
  for (int f = 0; f < ND; ++f) {
    float x = db[f * RW + lane];
    sv += x; sv2 = fmaf(x, x, sv2);
  }

  float part = fmaf(sv, sv, -sv2);  // sv*sv - sv2, per element

  // reduce part & lin across the 32-lane group (xor masks <32 stay in-half)
#pragma unroll
  for (int m = 16; m > 0; m >>= 1) {
    part += __shfl_xor(part, m, 64);
    lin  += __shfl_xor(lin,  m, 64);
  }

  if (lane == 0) {
    float logit = fmaf(0.5f, part, lin);
    out[samp] = 1.f / (1.f + expf(-logit));
  }
}

extern "C" void kernel_launch(void* const* d_in, const int* in_sizes, int n_in,
                              void* d_out, int out_size, void* d_ws, size_t ws_size,
                              hipStream_t stream) {
  const float* user = (const float*)d_in[0];
  const float* ctx  = (const float*)d_in[1];
  const float* doc  = (const float*)d_in[2];
  float* out = (float*)d_out;

  // 256 threads = 8 samples/block; 16384 samples -> 2048 blocks
  dim3 block(256);
  dim3 grid(NS / 8);
  fm_kernel<<<grid, block, 0, stream>>>(user, ctx, doc, out);
}

// Round 4
// 144.837 us; speedup vs baseline: 1.0599x; 1.0599x over previous
//
#include <hip/hip_runtime.h>
#include <hip/hip_bf16.h>
#include <math.h>

// FM model: out[s] = sigmoid(0.5*sum_e((sum_f v[s,f,e])^2 - sum_f v[s,f,e]^2)
//                           + sum_f linear[s,f])
// user[16384,20,33], ctx[16384,10,33], doc[16384,30,33]; v=[:,:,0:32], linear=[:,:,32]
//
// R3 finding: direct per-lane dword loads (forced by the 33-float row stride)
// plateau at 2.3 TB/s — the MI355X scalar-load-stream ceiling. Fix: stage the
// contiguous per-sample blobs into LDS with coalesced float4 loads (global
// side is dense and 16B-aligned at even-sample granularity), then do the
// stride-33 element reads from LDS (stride 33 dwords = bank-conflict-free).
//
// Layout: 128-thread blocks = 2 independent waves. Each wave owns 2 samples
// and a private 15,840B LDS region -> NO __syncthreads, only intra-wave
// lgkmcnt ordering. 31.7KB LDS/block -> 5 blocks/CU = 10 waves/CU, each with
// ~17 outstanding dwordx4 (17KB in flight/wave >> BW-latency product).

#define NS 16384
#define RW 33
// per-sample floats: user 20*33=660, ctx 10*33=330, doc 30*33=990 (total 1980)

__global__ __launch_bounds__(128) void fm_kernel(
    const float* __restrict__ user,
    const float* __restrict__ ctx,
    const float* __restrict__ doc,
    float* __restrict__ out) {
  // 2 waves x 3960 floats = 7920 floats = 31,680 B
  __shared__ float smem[7920];

  const int tid  = threadIdx.x;
  const int w    = tid >> 6;    // wave id (0..1)
  const int lane = tid & 63;

  // wave-private LDS region
  float* lu = smem + w * 3960;  // user pair: 1320 floats (330 float4)
  float* lc = lu + 1320;        // ctx  pair:  660 floats (165 float4)
  float* ld = lc + 660;         // doc  pair: 1980 floats (495 float4)

  const int spair = blockIdx.x * 4 + 2 * w;  // first sample of this wave's pair (even)

  // global chunk bases — spair is even, so all are 16B-aligned
  const float4* gu = (const float4*)(user + (size_t)spair * 660);  // 330 float4
  const float4* gc = (const float4*)(ctx  + (size_t)spair * 330);  // 165 float4
  const float4* gd = (const float4*)(doc  + (size_t)spair * 990);  // 495 float4

  float4* su4 = (float4*)lu;
  float4* sc4 = (float4*)lc;
  float4* sd4 = (float4*)ld;

  // stage: coalesced float4, 64 lanes, predicated tails
#pragma unroll
  for (int i = 0; i < 6; ++i) {           // 330 float4
    int idx = i * 64 + lane;
    if (idx < 330) su4[idx] = gu[idx];
  }
#pragma unroll
  for (int i = 0; i < 3; ++i) {           // 165 float4
    int idx = i * 64 + lane;
    if (idx < 165) sc4[idx] = gc[idx];
  }
#pragma unroll
  for (int i = 0; i < 8; ++i) {           // 495 float4
    int idx = i * 64 + lane;
    if (idx < 495) sd4[idx] = gd[idx];
  }
  // no __syncthreads: LDS region is wave-private; compiler orders via lgkmcnt

  const int sel = lane >> 5;   // which sample of the pair
  const int e   = lane & 31;   // latent element owned by this lane

  const float* mu = lu + sel * 660;
  const float* mc = lc + sel * 330;
  const float* md = ld + sel * 990;

  float sv = 0.f, sv2 = 0.f, lin = 0.f;

#pragma unroll
  for (int f = 0; f < 20; ++f) {
    float x = mu[f * RW + e];
    sv += x; sv2 = fmaf(x, x, sv2);
  }
#pragma unroll
  for (int f = 0; f < 10; ++f) {
    float x = mc[f * RW + e];
    sv += x; sv2 = fmaf(x, x, sv2);
  }
#pragma unroll
  for (int f = 0; f < 30; ++f) {
    float x = md[f * RW + e];
    sv += x; sv2 = fmaf(x, x, sv2);
  }

  // linear terms: lane e reads row e's col 32 (stride 33 dwords = conflict-free)
  if (e < 20) lin += mu[e * RW + 32];
  if (e < 10) lin += mc[e * RW + 32];
  /* e < 30 */
  if (e < 30) lin += md[e * RW + 32];

  float part = fmaf(sv, sv, -sv2);  // S_e^2 - Q_e

  // reduce part & lin over the 32-lane half (masks <32 stay within each half)
#pragma unroll
  for (int m = 16; m > 0; m >>= 1) {
    part += __shfl_xor(part, m, 64);
    lin  += __shfl_xor(lin,  m, 64);
  }

  if (e == 0) {
    float logit = fmaf(0.5f, part, lin);
    out[spair + sel] = 1.f / (1.f + expf(-logit));
  }
}

extern "C" void kernel_launch(void* const* d_in, const int* in_sizes, int n_in,
                              void* d_out, int out_size, void* d_ws, size_t ws_size,
                              hipStream_t stream) {
  const float* user = (const float*)d_in[0];
  const float* ctx  = (const float*)d_in[1];
  const float* doc  = (const float*)d_in[2];
  float* out = (float*)d_out;

  // 4 samples/block (2 per wave), 16384 samples -> 4096 blocks
  dim3 block(128);
  dim3 grid(NS / 4);
  fm_kernel<<<grid, block, 0, stream>>>(user, ctx, doc, out);
}

// Round 5
// 142.633 us; speedup vs baseline: 1.0763x; 1.0154x over previous
//
#include <hip/hip_runtime.h>
#include <hip/hip_bf16.h>
#include <math.h>

// FM model: out[s] = sigmoid(0.5*sum_e((sum_f v[s,f,e])^2 - sum_f v[s,f,e]^2)
//                           + sum_f linear[s,f])
// user[16384,20,33], ctx[16384,10,33], doc[16384,30,33]; v=[:,:,0:32], linear=[:,:,32]
//
// R4 post-mortem: LDS float4 staging fixed coalescing (FETCH = ideal) but
// occupancy fell to 20% (15.8KB LDS/wave -> 2.5 waves/SIMD) and each wave
// full-stalls on its own loads. R5: ONE sample per wave (7.9KB LDS/wave),
// 128-thread block stages a sample PAIR cooperatively (pair keeps all global
// bases 16B-aligned), wave w computes sample w with fields split across its
// two 32-lane halves. 15.84KB/block -> 10 blocks/CU = 5 waves/SIMD (2x R4),
// half the per-wave serial work -> ~4x better stall coverage.

#define NS 16384

__global__ __launch_bounds__(128) void fm_kernel(
    const float* __restrict__ user,
    const float* __restrict__ ctx,
    const float* __restrict__ doc,
    float* __restrict__ out) {
  // pair blob: user-pair 1320 + ctx-pair 660 + doc-pair 1980 = 3960 floats
  __shared__ float smem[3960];

  const int tid = threadIdx.x;
  const int spair = blockIdx.x * 2;  // even sample index

  // ---- cooperative staging: 990 float4, all pair bases 16B-aligned ----
  const float4* gu = (const float4*)(user + (size_t)spair * 660);  // 330 f4
  const float4* gc = (const float4*)(ctx  + (size_t)spair * 330);  // 165 f4
  const float4* gd = (const float4*)(doc  + (size_t)spair * 990);  // 495 f4
  float4* su = (float4*)smem;           // [0, 330)
  float4* sc = (float4*)(smem + 1320);  // [330, 495) in f4 units
  float4* sd = (float4*)(smem + 1980);  // [495, 990)

  // load-all-then-store-all per segment to maximize outstanding loads
  {
    float4 r0 = gu[tid], r1 = gu[128 + tid];
    float4 r2, r3, r4, r5, r6, r7;
    bool pu = (256 + tid) < 330;               // u tail: 74
    if (pu) r2 = gu[256 + tid];
    r3 = gc[tid];
    bool pc = (128 + tid) < 165;               // c tail: 37
    if (pc) r4 = gc[128 + tid];
    r5 = gd[tid];
    r6 = gd[128 + tid];
    r7 = gd[256 + tid];
    bool pd = (384 + tid) < 495;               // d tail: 111
    float4 r8;
    if (pd) r8 = gd[384 + tid];

    su[tid] = r0;
    su[128 + tid] = r1;
    if (pu) su[256 + tid] = r2;
    sc[tid] = r3;
    if (pc) sc[128 + tid] = r4;
    sd[tid] = r5;
    sd[128 + tid] = r6;
    sd[256 + tid] = r7;
    if (pd) sd[384 + tid] = r8;
  }
  __syncthreads();

  // ---- compute: wave w owns sample spair+w ----
  const int w = tid >> 6;       // wave id (0..1)
  const int l = tid & 63;       // lane in wave
  const int h = l >> 5;         // field-half (0: rows 0-29, 1: rows 30-59)
  const int e = l & 31;         // latent element owned by this lane

  const float* mu = smem + w * 660;           // sample's user rows (20x33)
  const float* mc = smem + 1320 + w * 330;    // ctx rows (10x33)
  const float* md = smem + 1980 + w * 990;    // doc rows (30x33)

  // half 0: 20 user rows then 10 ctx rows; half 1: 20+10 doc rows
  const float* p1 = (h ? md : mu) + e;
  const float* p2 = (h ? (md + 660) : mc) + e;

  float sv = 0.f, sv2 = 0.f;
#pragma unroll
  for (int f = 0; f < 20; ++f) {
    float x = p1[f * 33];
    sv += x; sv2 = fmaf(x, x, sv2);
  }
#pragma unroll
  for (int f = 0; f < 10; ++f) {
    float x = p2[f * 33];
    sv += x; sv2 = fmaf(x, x, sv2);
  }

  // linear terms (col 32): half 0 covers rows 0-29, half 1 rows 30-59
  float lin = 0.f;
  if (h == 0) {
    if (e < 20)      lin = mu[e * 33 + 32];
    else if (e < 30) lin = mc[(e - 20) * 33 + 32];
  } else {
    if (e < 30)      lin = md[e * 33 + 32];
  }

  // merge the two field-halves (mask 32 crosses halves)
  float svT  = sv  + __shfl_xor(sv,  32, 64);
  float sv2T = sv2 + __shfl_xor(sv2, 32, 64);
  float linT = lin + __shfl_xor(lin, 32, 64);

  float part = fmaf(svT, svT, -sv2T);  // S_e^2 - Q_e (identical in both halves)

  // reduce over the 32 elements (masks <32 stay within each half)
#pragma unroll
  for (int m = 16; m > 0; m >>= 1) {
    part += __shfl_xor(part, m, 64);
    linT += __shfl_xor(linT, m, 64);
  }

  if (l == 0) {
    float logit = fmaf(0.5f, part, linT);
    out[spair + w] = 1.f / (1.f + expf(-logit));
  }
}

extern "C" void kernel_launch(void* const* d_in, const int* in_sizes, int n_in,
                              void* d_out, int out_size, void* d_ws, size_t ws_size,
                              hipStream_t stream) {
  const float* user = (const float*)d_in[0];
  const float* ctx  = (const float*)d_in[1];
  const float* doc  = (const float*)d_in[2];
  float* out = (float*)d_out;

  // 2 samples/block (1 per wave), 16384 samples -> 8192 blocks
  dim3 block(128);
  dim3 grid(NS / 2);
  fm_kernel<<<grid, block, 0, stream>>>(user, ctx, doc, out);
}